// Round 1
// baseline (689.458 us; speedup 1.0000x reference)
//
#include <hip/hip_runtime.h>

// HashEncoder forward, R4: fully fused single-pass.
// - Pass 0: fp32 -> packed bf16x2 table (28.5 MB; hashed level = 2 MiB/level).
// - Pass 1 (hashenc_fused): thread = point, loops all 16 levels.
//   * input read ONCE per point (was 16x in the per-level kernel; enc_level was
//     request-rate-bound at 10.6% HBM / 13.8% VALU / 88% occ, so lane-address
//     count is the currency: 3 input loads amortize 48->3 per point).
//   * parity pair-load kept: x-prime==1 so even gx covers both x-corners with
//     one aligned uint2; odd-gx 4B loads exec-masked. ~6 line-req/point-level.
//   * output: no stage/transpose kernel. Levels 0-7 staged in an 18 KB LDS
//     tile, then 4 coalesced float4 stores (64B halves of each 128B out row);
//     repeat for levels 8-15. Saves 268 MB HBM round-trip + a launch.
// - LDS 18 KB + launch_bounds(256,8) => 8 blocks/CU, 32 waves/CU.

static constexpr uint32_t P1 = 2654435761u;
static constexpr uint32_t P2 = 805459861u;
static constexpr uint32_t NPARAMS = 7114752u;
static constexpr uint32_t HMASK = 524287u;

// ---------- pass 0 ----------
__device__ inline uint32_t bf16_bits(float f) {
    uint32_t u = __float_as_uint(f);
    return (u + 0x7FFFu + ((u >> 16) & 1u)) >> 16;
}

__global__ __launch_bounds__(256) void convert_bf16(
    const float* __restrict__ emb, uint32_t* __restrict__ tab)
{
    const uint32_t i = blockIdx.x * 256u + threadIdx.x;   // float4 index
    const float4 v = ((const float4*)emb)[i];
    uint2 o;
    o.x = bf16_bits(v.x) | (bf16_bits(v.y) << 16);
    o.y = bf16_bits(v.z) | (bf16_bits(v.w) << 16);
    ((uint2*)tab)[i] = o;
}

// ---------- per-level encode (same math as R3 enc_level) ----------
__device__ __forceinline__ float2 enc_point_level(
    const float x01, const float y01, const float z01,
    const uint32_t l, const uint32_t* __restrict__ tab)
{
    const uint32_t res = 16u << l;
    const float scale = (float)(res - 1u);

    const float posx = x01 * scale + 0.5f;
    const float posy = y01 * scale + 0.5f;
    const float posz = z01 * scale + 0.5f;

    const float fgx = floorf(posx), fgy = floorf(posy), fgz = floorf(posz);
    const float fx = posx - fgx, fy = posy - fgy, fz = posz - fgz;
    const uint32_t gx = (uint32_t)fgx, gy = (uint32_t)fgy, gz = (uint32_t)fgz;

    uint32_t off;
    if (l >= 3u)      off = 299008u + (l - 3u) * 524288u;
    else if (l == 2u) off = 36864u;
    else if (l == 1u) off = 4096u;
    else              off = 0u;
    const bool hashed = (l >= 3u);
    const uint32_t s = 4u + (hashed ? 0u : l);

    const float wx0 = 1.0f - fx, wx1 = fx;
    const float wy[2] = {1.0f - fy, fy};
    const float wz[2] = {1.0f - fz, fz};

    // per-(y,z) index contributions
    uint32_t yzc[4];
    if (hashed) {
        const uint32_t hy0 = gy * P1, hy1 = hy0 + P1;
        const uint32_t hz0 = gz * P2, hz1 = hz0 + P2;
        yzc[0] = hy0 ^ hz0; yzc[1] = hy1 ^ hz0;
        yzc[2] = hy0 ^ hz1; yzc[3] = hy1 ^ hz1;
    } else {
        const uint32_t dy0 = gy << s, dy1 = dy0 + (1u << s);
        const uint32_t dz0 = gz << (2u * s), dz1 = dz0 + (1u << (2u * s));
        yzc[0] = dy0 + dz0; yzc[1] = dy1 + dz0;
        yzc[2] = dy0 + dz1; yzc[3] = dy1 + dz1;
    }

    const bool gx_odd = (gx & 1u) != 0u;

    uint32_t idxA[4], idxB[4];
#pragma unroll
    for (int c = 0; c < 4; ++c) {
        if (hashed) {
            idxA[c] = (gx ^ yzc[c]) & HMASK;
            idxB[c] = ((gx + 1u) ^ yzc[c]) & HMASK;
        } else {
            idxA[c] = gx + yzc[c];
            idxB[c] = idxA[c] + 1u;
        }
    }

    // pair loads (always; covers both x-corners when gx even)
    uint2 pr[4];
#pragma unroll
    for (int c = 0; c < 4; ++c)
        pr[c] = *(const uint2*)(tab + off + (idxA[c] & ~1u));

    // odd-gx extra loads, exec-masked so even lanes issue no requests
    uint32_t vBo[4];
    if (gx_odd) {
#pragma unroll
        for (int c = 0; c < 4; ++c)
            vBo[c] = tab[off + idxB[c]];
    }

    float sx = 0.0f, sy = 0.0f;
#pragma unroll
    for (int c = 0; c < 4; ++c) {
        const uint32_t lo = idxA[c] & 1u;
        const uint32_t vA = lo ? pr[c].y : pr[c].x;
        const uint32_t vBe = lo ? pr[c].x : pr[c].y;   // idxA^1, valid iff gx even
        const uint32_t vB = gx_odd ? vBo[c] : vBe;
        const float wyz = wy[c & 1] * wz[c >> 1];
        const float eAx = __uint_as_float(vA << 16);
        const float eAy = __uint_as_float(vA & 0xFFFF0000u);
        const float eBx = __uint_as_float(vB << 16);
        const float eBy = __uint_as_float(vB & 0xFFFF0000u);
        sx = fmaf(wyz, fmaf(wx0, eAx, wx1 * eBx), sx);
        sy = fmaf(wyz, fmaf(wx0, eAy, wx1 * eBy), sy);
    }
    return make_float2(sx, sy);
}

// ---------- pass 1: fused all-level encode + in-LDS transpose ----------
__global__ __launch_bounds__(256, 8) void hashenc_fused(
    const float* __restrict__ inp,
    const uint32_t* __restrict__ tab,
    float4* __restrict__ out4)
{
    // stride 9 float2 (=18 words): 4-way on staging writes, 2-way on reads —
    // negligible vs ~96 global gathers/point.
    __shared__ float2 t[256][9];

    const uint32_t tid = threadIdx.x;
    const uint32_t p0 = blockIdx.x * 256u;
    const uint32_t p = p0 + tid;

    const float x01 = (inp[p * 3u + 0u] + 1.0f) * 0.5f;
    const float y01 = (inp[p * 3u + 1u] + 1.0f) * 0.5f;
    const float z01 = (inp[p * 3u + 2u] + 1.0f) * 0.5f;

#pragma unroll
    for (uint32_t ph = 0u; ph < 2u; ++ph) {
        if (ph) __syncthreads();            // protect t from prior read phase

#pragma unroll
        for (uint32_t j = 0u; j < 8u; ++j)
            t[tid][j] = enc_point_level(x01, y01, z01, ph * 8u + j, tab);

        __syncthreads();

        // coalesced 64B-half writes: 4 iters x 256 threads x float4 = 4KB/iter
#pragma unroll
        for (uint32_t k = 0u; k < 4u; ++k) {
            const uint32_t pl = k * 64u + (tid >> 2);
            const uint32_t c = tid & 3u;
            const float2 a = t[pl][2u * c];
            const float2 b = t[pl][2u * c + 1u];
            out4[(size_t)(p0 + pl) * 8u + ph * 4u + c] =
                make_float4(a.x, a.y, b.x, b.y);
        }
    }
}

// ---------- fallback: single-pass (R1) ----------
__global__ __launch_bounds__(256) void hashenc_fwd(
    const float* __restrict__ inp, const float* __restrict__ emb,
    float* __restrict__ out, int npoints)
{
    const uint32_t tid = blockIdx.x * 256u + threadIdx.x;
    const uint32_t p = tid >> 4, l = tid & 15u;
    if (p >= (uint32_t)npoints) return;
    const float x01 = (inp[p * 3u + 0u] + 1.0f) * 0.5f;
    const float y01 = (inp[p * 3u + 1u] + 1.0f) * 0.5f;
    const float z01 = (inp[p * 3u + 2u] + 1.0f) * 0.5f;
    const uint32_t res = 16u << l;
    const float scale = (float)(res - 1u);
    const float posx = x01 * scale + 0.5f, posy = y01 * scale + 0.5f, posz = z01 * scale + 0.5f;
    const float fgx = floorf(posx), fgy = floorf(posy), fgz = floorf(posz);
    const float fx = posx - fgx, fy = posy - fgy, fz = posz - fgz;
    const uint32_t gx = (uint32_t)fgx, gy = (uint32_t)fgy, gz = (uint32_t)fgz;
    uint32_t off;
    if (l >= 3u)      off = 299008u + (l - 3u) * 524288u;
    else if (l == 2u) off = 36864u;
    else if (l == 1u) off = 4096u;
    else              off = 0u;
    const bool hashed = (l >= 3u);
    const uint32_t s = 4u + (hashed ? 0u : l);
    const float wx[2] = {1.0f - fx, fx}, wy[2] = {1.0f - fy, fy}, wz[2] = {1.0f - fz, fz};
    float2 g[8]; float w[8];
#pragma unroll
    for (int c = 0; c < 8; ++c) {
        const uint32_t bx = (uint32_t)c & 1u, by = ((uint32_t)c >> 1) & 1u, bz = ((uint32_t)c >> 2) & 1u;
        const uint32_t cx = gx + bx, cy = gy + by, cz = gz + bz;
        const uint32_t hidx = (cx ^ (cy * P1) ^ (cz * P2)) & HMASK;
        const uint32_t didx = cx + (cy << s) + (cz << (2u * s));
        const uint32_t idx  = hashed ? hidx : didx;
        w[c] = wx[bx] * wy[by] * wz[bz];
        g[c] = *(const float2*)(emb + 2u * (off + idx));
    }
    float sx = 0.0f, sy = 0.0f;
#pragma unroll
    for (int c = 0; c < 8; ++c) { sx = fmaf(w[c], g[c].x, sx); sy = fmaf(w[c], g[c].y, sy); }
    *(float2*)(out + (size_t)p * 32u + (size_t)l * 2u) = make_float2(sx, sy);
}

extern "C" void kernel_launch(void* const* d_in, const int* in_sizes, int n_in,
                              void* d_out, int out_size, void* d_ws, size_t ws_size,
                              hipStream_t stream) {
    const float* inp = (const float*)d_in[0];
    const float* emb = (const float*)d_in[1];
    float* out = (float*)d_out;
    const int npoints = in_sizes[0] / 3;

    const size_t tab_bytes = (size_t)NPARAMS * 4u;

    if (ws_size >= tab_bytes && (npoints & 255) == 0) {
        uint32_t* tab = (uint32_t*)d_ws;

        const int conv_units = (int)(NPARAMS * 2u / 4u);   // float4 count
        convert_bf16<<<(conv_units + 255) / 256, 256, 0, stream>>>(emb, tab);

        hashenc_fused<<<npoints / 256, 256, 0, stream>>>(inp, tab, (float4*)out);
    } else {
        const int total = npoints * 16;
        hashenc_fwd<<<(total + 255) / 256, 256, 0, stream>>>(inp, emb, out, npoints);
    }
}

// Round 2
// 590.718 us; speedup vs baseline: 1.1672x; 1.1672x over previous
//
#include <hip/hip_runtime.h>

// HashEncoder forward, R5.
// R4 post-mortem: full fusion destroyed per-XCD L2 table locality
// (FETCH 197MB -> 1.7GB, HBM 42%). The per-level dispatch (blockIdx.y = level,
// x-major dispatch => ~1 level's 2MiB table active per XCD L2) is load-bearing.
// R5 reverts to the R3 3-pass structure and attacks enc_level's latency bound:
// 14.5 cy/point-level ~= (one wave = ~10 VMEM issue + ~500cy gather latency)
// / 7 waves/SIMD. Fix = 2 points/thread with all gathers issued before any
// consumption: ~2x loads in flight per wave, 8 instr/pl instead of 10.
// - Pass 0: fp32 -> packed bf16x2 table (28.5 MB).
// - Pass 1 (enc_level2): 2 points x 1 level per thread; parity pair-load
//   (x-prime==1: even gx covers both x-corners with one aligned uint2).
// - Pass 2: LDS-tiled transpose [16][np] -> [np][32].

static constexpr uint32_t P1 = 2654435761u;
static constexpr uint32_t P2 = 805459861u;
static constexpr uint32_t NPARAMS = 7114752u;
static constexpr uint32_t HMASK = 524287u;

// ---------- pass 0 ----------
__device__ inline uint32_t bf16_bits(float f) {
    uint32_t u = __float_as_uint(f);
    return (u + 0x7FFFu + ((u >> 16) & 1u)) >> 16;
}

__global__ __launch_bounds__(256) void convert_bf16(
    const float* __restrict__ emb, uint32_t* __restrict__ tab)
{
    const uint32_t i = blockIdx.x * 256u + threadIdx.x;   // float4 index
    const float4 v = ((const float4*)emb)[i];
    uint2 o;
    o.x = bf16_bits(v.x) | (bf16_bits(v.y) << 16);
    o.y = bf16_bits(v.z) | (bf16_bits(v.w) << 16);
    ((uint2*)tab)[i] = o;
}

// ---------- pass 1: 2 points x 1 level per thread ----------
__global__ __launch_bounds__(256) void enc_level2(
    const float* __restrict__ inp,
    const uint32_t* __restrict__ tab,   // packed bf16x2 per row
    float2* __restrict__ stage,         // [16][np]
    int npoints)
{
    const uint32_t l = blockIdx.y;
    const uint32_t pair = blockIdx.x * 256u + threadIdx.x;   // point pair index

    // input: 3x float2 covering points 2*pair, 2*pair+1 (24B, 8B-aligned)
    const float2* in2 = (const float2*)inp;
    const float2 ab = in2[3u * pair + 0u];   // x0 y0
    const float2 cd = in2[3u * pair + 1u];   // z0 x1
    const float2 ef = in2[3u * pair + 2u];   // y1 z1

    const uint32_t res = 16u << l;
    const float scale = (float)(res - 1u);

    uint32_t off;
    if (l >= 3u)      off = 299008u + (l - 3u) * 524288u;
    else if (l == 2u) off = 36864u;
    else if (l == 1u) off = 4096u;
    else              off = 0u;
    const bool hashed = (l >= 3u);
    const uint32_t s = 4u + (hashed ? 0u : l);

    const float xs[2] = {ab.x, cd.y};
    const float ys[2] = {ab.y, ef.x};
    const float zs[2] = {cd.x, ef.y};

    float wx0[2], wx1[2], wyq[2][2], wzq[2][2];
    uint32_t idxA[2][4];
    bool gx_odd[2];
    uint32_t gxq[2];

    // ---- phase A: addresses + weights for both points ----
#pragma unroll
    for (int q = 0; q < 2; ++q) {
        const float x01 = (xs[q] + 1.0f) * 0.5f;
        const float y01 = (ys[q] + 1.0f) * 0.5f;
        const float z01 = (zs[q] + 1.0f) * 0.5f;
        const float posx = x01 * scale + 0.5f;
        const float posy = y01 * scale + 0.5f;
        const float posz = z01 * scale + 0.5f;
        const float fgx = floorf(posx), fgy = floorf(posy), fgz = floorf(posz);
        const float fx = posx - fgx, fy = posy - fgy, fz = posz - fgz;
        const uint32_t gx = (uint32_t)fgx, gy = (uint32_t)fgy, gz = (uint32_t)fgz;

        wx0[q] = 1.0f - fx; wx1[q] = fx;
        wyq[q][0] = 1.0f - fy; wyq[q][1] = fy;
        wzq[q][0] = 1.0f - fz; wzq[q][1] = fz;
        gxq[q] = gx;
        gx_odd[q] = (gx & 1u) != 0u;

        uint32_t yzc[4];
        if (hashed) {
            const uint32_t hy0 = gy * P1, hy1 = hy0 + P1;
            const uint32_t hz0 = gz * P2, hz1 = hz0 + P2;
            yzc[0] = hy0 ^ hz0; yzc[1] = hy1 ^ hz0;
            yzc[2] = hy0 ^ hz1; yzc[3] = hy1 ^ hz1;
        } else {
            const uint32_t dy0 = gy << s, dy1 = dy0 + (1u << s);
            const uint32_t dz0 = gz << (2u * s), dz1 = dz0 + (1u << (2u * s));
            yzc[0] = dy0 + dz0; yzc[1] = dy1 + dz0;
            yzc[2] = dy0 + dz1; yzc[3] = dy1 + dz1;
        }
#pragma unroll
        for (int c = 0; c < 4; ++c)
            idxA[q][c] = hashed ? ((gxq[q] ^ yzc[c]) & HMASK)
                                : (gxq[q] + yzc[c]);
    }

    // ---- phase B: issue all 8 pair loads before any consumption ----
    uint2 pr[2][4];
#pragma unroll
    for (int q = 0; q < 2; ++q)
#pragma unroll
        for (int c = 0; c < 4; ++c)
            pr[q][c] = *(const uint2*)(tab + off + (idxA[q][c] & ~1u));

    // ---- phase C: odd-gx extra loads, exec-masked ----
    uint32_t vBo[2][4];
#pragma unroll
    for (int q = 0; q < 2; ++q) {
        if (gx_odd[q]) {
#pragma unroll
            for (int c = 0; c < 4; ++c) {
                const uint32_t idxB = hashed
                    ? (((gxq[q] + 1u) ^ (idxA[q][c] ^ gxq[q])) & HMASK)
                    : (idxA[q][c] + 1u);
                vBo[q][c] = tab[off + idxB];
            }
        }
    }

    // ---- phase D: weighted reduction for both points ----
    float4 r;
    float* rp = (float*)&r;
#pragma unroll
    for (int q = 0; q < 2; ++q) {
        float sx = 0.0f, sy = 0.0f;
#pragma unroll
        for (int c = 0; c < 4; ++c) {
            const uint32_t lo = idxA[q][c] & 1u;
            const uint32_t vA = lo ? pr[q][c].y : pr[q][c].x;
            const uint32_t vBe = lo ? pr[q][c].x : pr[q][c].y;  // idxA^1, valid iff gx even
            const uint32_t vB = gx_odd[q] ? vBo[q][c] : vBe;
            const float wyz = wyq[q][c & 1] * wzq[q][c >> 1];
            const float eAx = __uint_as_float(vA << 16);
            const float eAy = __uint_as_float(vA & 0xFFFF0000u);
            const float eBx = __uint_as_float(vB << 16);
            const float eBy = __uint_as_float(vB & 0xFFFF0000u);
            sx = fmaf(wyz, fmaf(wx0[q], eAx, wx1[q] * eBx), sx);
            sy = fmaf(wyz, fmaf(wx0[q], eAy, wx1[q] * eBy), sy);
        }
        rp[2 * q + 0] = sx;
        rp[2 * q + 1] = sy;
    }

    // one float4 store: stage[l][2*pair .. 2*pair+1]
    ((float4*)stage)[(size_t)l * ((uint32_t)npoints >> 1) + pair] = r;
}

// ---------- pass 2: LDS-tiled transpose ----------
__global__ __launch_bounds__(256) void transpose_out(
    const float2* __restrict__ stage, float4* __restrict__ out4, int npoints)
{
    __shared__ float2 t[256][17];   // +1 pad: 2 lanes/bank on load phase (free)
    const uint32_t p0 = blockIdx.x * 256u;
    const uint32_t tid = threadIdx.x;

#pragma unroll
    for (int l = 0; l < 16; ++l)
        t[tid][l] = stage[(size_t)l * (uint32_t)npoints + p0 + tid];  // coalesced 2KB
    __syncthreads();

#pragma unroll
    for (int k = 0; k < 8; ++k) {
        const uint32_t f = (uint32_t)k * 256u + tid;
        const uint32_t p = f >> 3, c = f & 7u;
        const float2 a = t[p][2u * c];
        const float2 b = t[p][2u * c + 1u];
        out4[(size_t)(p0 + p) * 8u + c] = make_float4(a.x, a.y, b.x, b.y);  // coalesced 4KB
    }
}

// ---------- fallback: single-pass (R1) ----------
__global__ __launch_bounds__(256) void hashenc_fwd(
    const float* __restrict__ inp, const float* __restrict__ emb,
    float* __restrict__ out, int npoints)
{
    const uint32_t tid = blockIdx.x * 256u + threadIdx.x;
    const uint32_t p = tid >> 4, l = tid & 15u;
    if (p >= (uint32_t)npoints) return;
    const float x01 = (inp[p * 3u + 0u] + 1.0f) * 0.5f;
    const float y01 = (inp[p * 3u + 1u] + 1.0f) * 0.5f;
    const float z01 = (inp[p * 3u + 2u] + 1.0f) * 0.5f;
    const uint32_t res = 16u << l;
    const float scale = (float)(res - 1u);
    const float posx = x01 * scale + 0.5f, posy = y01 * scale + 0.5f, posz = z01 * scale + 0.5f;
    const float fgx = floorf(posx), fgy = floorf(posy), fgz = floorf(posz);
    const float fx = posx - fgx, fy = posy - fgy, fz = posz - fgz;
    const uint32_t gx = (uint32_t)fgx, gy = (uint32_t)fgy, gz = (uint32_t)fgz;
    uint32_t off;
    if (l >= 3u)      off = 299008u + (l - 3u) * 524288u;
    else if (l == 2u) off = 36864u;
    else if (l == 1u) off = 4096u;
    else              off = 0u;
    const bool hashed = (l >= 3u);
    const uint32_t s = 4u + (hashed ? 0u : l);
    const float wx[2] = {1.0f - fx, fx}, wy[2] = {1.0f - fy, fy}, wz[2] = {1.0f - fz, fz};
    float2 g[8]; float w[8];
#pragma unroll
    for (int c = 0; c < 8; ++c) {
        const uint32_t bx = (uint32_t)c & 1u, by = ((uint32_t)c >> 1) & 1u, bz = ((uint32_t)c >> 2) & 1u;
        const uint32_t cx = gx + bx, cy = gy + by, cz = gz + bz;
        const uint32_t hidx = (cx ^ (cy * P1) ^ (cz * P2)) & HMASK;
        const uint32_t didx = cx + (cy << s) + (cz << (2u * s));
        const uint32_t idx  = hashed ? hidx : didx;
        w[c] = wx[bx] * wy[by] * wz[bz];
        g[c] = *(const float2*)(emb + 2u * (off + idx));
    }
    float sx = 0.0f, sy = 0.0f;
#pragma unroll
    for (int c = 0; c < 8; ++c) { sx = fmaf(w[c], g[c].x, sx); sy = fmaf(w[c], g[c].y, sy); }
    *(float2*)(out + (size_t)p * 32u + (size_t)l * 2u) = make_float2(sx, sy);
}

extern "C" void kernel_launch(void* const* d_in, const int* in_sizes, int n_in,
                              void* d_out, int out_size, void* d_ws, size_t ws_size,
                              hipStream_t stream) {
    const float* inp = (const float*)d_in[0];
    const float* emb = (const float*)d_in[1];
    float* out = (float*)d_out;
    const int npoints = in_sizes[0] / 3;

    const size_t tab_bytes = (size_t)NPARAMS * 4u;
    const size_t stage_bytes = (size_t)npoints * 16u * 8u;
    const size_t need = tab_bytes + stage_bytes;

    if (ws_size >= need && (npoints & 511) == 0) {
        uint32_t* tab = (uint32_t*)d_ws;
        float2* stage = (float2*)((char*)d_ws + tab_bytes);

        const int conv_units = (int)(NPARAMS * 2u / 4u);
        convert_bf16<<<(conv_units + 255) / 256, 256, 0, stream>>>(emb, tab);

        dim3 g1(npoints / 512, 16);
        enc_level2<<<g1, 256, 0, stream>>>(inp, tab, stage, npoints);

        transpose_out<<<npoints / 256, 256, 0, stream>>>(stage, (float4*)out, npoints);
    } else {
        const int total = npoints * 16;
        hashenc_fwd<<<(total + 255) / 256, 256, 0, stream>>>(inp, emb, out, npoints);
    }
}